// Round 1
// baseline (275.611 us; speedup 1.0000x reference)
//
#include <hip/hip_runtime.h>
#include <complex>
#include <cmath>

// ---------------- host-side CG table computation (exact port of reference) ----

static double fct(int n) { double r = 1.0; for (int i = 2; i <= n; ++i) r *= i; return r; }

static double su2_cg_coeff(int j1, int m1, int j2, int m2, int j3, int m3) {
    if (m3 != m1 + m2) return 0.0;
    int vmin = std::max(std::max(-j1 + j2 + m3, -j1 + m1), 0);
    int vmax = std::min(std::min(j2 + j3 + m1, j3 - j1 + j2), j3 + m3);
    double C = std::sqrt((2.0 * j3 + 1.0) * fct(j3 + j1 - j2) * fct(j3 - j1 + j2) * fct(j1 + j2 - j3)
                         * fct(j3 + m3) * fct(j3 - m3)
                         / (fct(j1 + j2 + j3 + 1) * fct(j1 - m1) * fct(j1 + m1) * fct(j2 - m2) * fct(j2 + m2)));
    double S = 0.0;
    for (int v = vmin; v <= vmax; ++v) {
        double sgn = ((v + j2 + m2) & 1) ? -1.0 : 1.0;
        S += sgn * fct(j2 + j3 + m1 - v) * fct(j1 - m1 + v)
             / (fct(v) * fct(j3 - j1 + j2 - v) * fct(j3 + m3 - v) * fct(v + j1 - j2 - m3));
    }
    return C * S;
}

// change-of-basis real->complex, rows = complex index (l+m), cols = real index
static void cob(int l, std::complex<double> q[5][5]) {
    for (int a = 0; a < 5; ++a) for (int b = 0; b < 5; ++b) q[a][b] = 0.0;
    const double is2 = 1.0 / std::sqrt(2.0);
    for (int m = -l; m < 0; ++m) {
        q[l + m][l - m] = is2;                                // col l+|m|
        q[l + m][l + m] = std::complex<double>(0.0, -is2);    // col l-|m|
    }
    q[l][l] = 1.0;
    for (int m = 1; m <= l; ++m) {
        double sgn = (m & 1) ? -1.0 : 1.0;
        q[l + m][l + m] = sgn * is2;                          // col l+|m|
        q[l + m][l - m] = std::complex<double>(0.0, sgn * is2); // col l-|m|
    }
    std::complex<double> ph;
    switch (l & 3) {
        case 0: ph = 1.0; break;
        case 1: ph = std::complex<double>(0.0, -1.0); break;
        case 2: ph = -1.0; break;
        default: ph = std::complex<double>(0.0, 1.0); break;
    }
    for (int a = 0; a < 5; ++a) for (int b = 0; b < 5; ++b) q[a][b] *= ph;
}

// real-basis wigner 3j, normalized to unit Frobenius norm. out is d1*d2*d3 row-major [j][l][m].
static void wigner3j(int l1, int l2, int l3, double* out) {
    int d1 = 2 * l1 + 1, d2 = 2 * l2 + 1, d3 = 2 * l3 + 1;
    double csu2[5][5][5] = {};
    for (int m1 = -l1; m1 <= l1; ++m1)
        for (int m2 = -l2; m2 <= l2; ++m2)
            if (std::abs(m1 + m2) <= l3)
                csu2[l1 + m1][l2 + m2][l3 + m1 + m2] =
                    su2_cg_coeff(l1, m1, l2, m2, l3, m1 + m2) / std::sqrt(2.0 * l3 + 1.0);
    std::complex<double> Q1[5][5], Q2[5][5], Q3[5][5];
    cob(l1, Q1); cob(l2, Q2); cob(l3, Q3);
    double nrm = 0.0;
    for (int j = 0; j < d1; ++j)
        for (int l = 0; l < d2; ++l)
            for (int m = 0; m < d3; ++m) {
                std::complex<double> s = 0.0;
                for (int i = 0; i < d1; ++i)
                    for (int k = 0; k < d2; ++k)
                        for (int n = 0; n < d3; ++n)
                            s += Q1[i][j] * Q2[k][l] * std::conj(Q3[n][m]) * csu2[i][k][n];
                out[(j * d2 + l) * d3 + m] = s.real();
                nrm += s.real() * s.real();
            }
    nrm = std::sqrt(nrm);
    for (int t = 0; t < d1 * d2 * d3; ++t) out[t] /= nrm;
}

struct CGTab {
    float cA;        // 0x0->0 scalar coefficient
    float B[9];      // 1x1->0 : [i*3+j]
    float Cjk[9];    // 0x1->1 : [j*3+k]
    float Dik[9];    // 1x0->1 : [i*3+k]
    float E[27];     // 1x1->1 : [(i*3+j)*3+k]
    float F[45];     // 1x1->2 : [(i*3+j)*5+k]
};

// ---------------- device kernel ---------------------------------------------
// Layout facts (derived from reference's raw reshapes, with mul1*mul2 == n == 2048):
//   out[r, c], r = u*32 + v, chunk col = chunk_base + nn*d3 + k3, nn in [0,2048)
//   x1_l0[u,nn]   = in1[(u*32 + nn/64)*256 + (nn%64)]
//   x1_l1[i,u,nn] = in1[(f/192)*256 + 64 + f%192],  f = i*131072 + u*2048 + nn
//   x2_l0[v,nn]   = in2[(v*64 + nn/32)*128 + (nn%32)]
//   x2_l1[j,v,nn] = in2[(g/96)*128 + 32 + g%96],    g = j*65536 + v*2048 + nn
// Sorted chunk bases: A(0e,0x0):0  B(0e,1x1):2048  C(1o,0x1):4096
//                     D(1o,1x0):10240  E(1e,1x1):16384  F(2e,1x1):22528

__global__ __launch_bounds__(256) void ftp_kernel(const float* __restrict__ in1,
                                                  const float* __restrict__ in2,
                                                  float* __restrict__ out,
                                                  CGTab cg) {
    const int nn = blockIdx.x * 256 + threadIdx.x;  // 0..2047
    const int r  = blockIdx.y;                      // 0..2047
    const int u  = r >> 5;
    const int v  = r & 31;

    const float a0 = in1[(u * 32 + (nn >> 6)) * 256 + (nn & 63)];
    const float b0 = in2[(v * 64 + (nn >> 5)) * 128 + (nn & 31)];

    float a1[3], b1[3];
#pragma unroll
    for (int i = 0; i < 3; ++i) {
        int f = i * 131072 + u * 2048 + nn;
        int row = f / 192, col = f - row * 192;
        a1[i] = in1[row * 256 + 64 + col];
    }
#pragma unroll
    for (int j = 0; j < 3; ++j) {
        int g = j * 65536 + v * 2048 + nn;
        int row = g / 96, col = g - row * 96;
        b1[j] = in2[row * 128 + 32 + col];
    }

    float* orow = out + (size_t)r * 32768;

    // A: 0e from 0x0
    orow[nn] = cg.cA * a0 * b0;

    // B: 0e from 1x1
    {
        float s = 0.f;
#pragma unroll
        for (int i = 0; i < 3; ++i)
#pragma unroll
            for (int j = 0; j < 3; ++j)
                s = fmaf(cg.B[i * 3 + j], a1[i] * b1[j], s);
        orow[2048 + nn] = s;
    }

    // C: 1o from 0x1
#pragma unroll
    for (int k = 0; k < 3; ++k) {
        float s = 0.f;
#pragma unroll
        for (int j = 0; j < 3; ++j) s = fmaf(cg.Cjk[j * 3 + k], b1[j], s);
        orow[4096 + nn * 3 + k] = a0 * s;
    }

    // D: 1o from 1x0
#pragma unroll
    for (int k = 0; k < 3; ++k) {
        float s = 0.f;
#pragma unroll
        for (int i = 0; i < 3; ++i) s = fmaf(cg.Dik[i * 3 + k], a1[i], s);
        orow[10240 + nn * 3 + k] = b0 * s;
    }

    // E: 1e from 1x1
#pragma unroll
    for (int k = 0; k < 3; ++k) {
        float s = 0.f;
#pragma unroll
        for (int i = 0; i < 3; ++i)
#pragma unroll
            for (int j = 0; j < 3; ++j)
                s = fmaf(cg.E[(i * 3 + j) * 3 + k], a1[i] * b1[j], s);
        orow[16384 + nn * 3 + k] = s;
    }

    // F: 2e from 1x1
#pragma unroll
    for (int k = 0; k < 5; ++k) {
        float s = 0.f;
#pragma unroll
        for (int i = 0; i < 3; ++i)
#pragma unroll
            for (int j = 0; j < 3; ++j)
                s = fmaf(cg.F[(i * 3 + j) * 5 + k], a1[i] * b1[j], s);
        orow[22528 + nn * 5 + k] = s;
    }
}

// ---------------- launch ------------------------------------------------------

extern "C" void kernel_launch(void* const* d_in, const int* in_sizes, int n_in,
                              void* d_out, int out_size, void* d_ws, size_t ws_size,
                              hipStream_t stream) {
    const float* in1 = (const float*)d_in[0];  // (2048, 256) fp32
    const float* in2 = (const float*)d_in[1];  // (2048, 128) fp32
    float* out = (float*)d_out;                // (2048, 32768) fp32

    // Host-side CG tables (pure CPU math — graph-capture safe; passed by value).
    CGTab cg;
    double w[45];
    const double s3 = std::sqrt(3.0), s5 = std::sqrt(5.0);

    wigner3j(0, 0, 0, w);
    cg.cA = (float)(w[0] * 1.0);

    wigner3j(1, 1, 0, w);  // [i][j][0]
    for (int i = 0; i < 3; ++i)
        for (int j = 0; j < 3; ++j) cg.B[i * 3 + j] = (float)(w[(i * 3 + j) * 1 + 0] * 1.0);

    wigner3j(0, 1, 1, w);  // [0][j][k]
    for (int j = 0; j < 3; ++j)
        for (int k = 0; k < 3; ++k) cg.Cjk[j * 3 + k] = (float)(w[j * 3 + k] * s3);

    wigner3j(1, 0, 1, w);  // [i][0][k]
    for (int i = 0; i < 3; ++i)
        for (int k = 0; k < 3; ++k) cg.Dik[i * 3 + k] = (float)(w[i * 3 + k] * s3);

    wigner3j(1, 1, 1, w);  // [i][j][k]
    for (int t = 0; t < 27; ++t) cg.E[t] = (float)(w[t] * s3);

    wigner3j(1, 1, 2, w);  // [i][j][k], d3 = 5
    for (int t = 0; t < 45; ++t) cg.F[t] = (float)(w[t] * s5);

    dim3 grid(2048 / 256, 2048, 1);
    dim3 block(256, 1, 1);
    ftp_kernel<<<grid, block, 0, stream>>>(in1, in2, out, cg);
}

// Round 2
// 263.744 us; speedup vs baseline: 1.0450x; 1.0450x over previous
//
#include <hip/hip_runtime.h>
#include <complex>
#include <cmath>

// ---------------- host-side CG table computation (exact port of reference) ----

static double fct(int n) { double r = 1.0; for (int i = 2; i <= n; ++i) r *= i; return r; }

static double su2_cg_coeff(int j1, int m1, int j2, int m2, int j3, int m3) {
    if (m3 != m1 + m2) return 0.0;
    int vmin = std::max(std::max(-j1 + j2 + m3, -j1 + m1), 0);
    int vmax = std::min(std::min(j2 + j3 + m1, j3 - j1 + j2), j3 + m3);
    double C = std::sqrt((2.0 * j3 + 1.0) * fct(j3 + j1 - j2) * fct(j3 - j1 + j2) * fct(j1 + j2 - j3)
                         * fct(j3 + m3) * fct(j3 - m3)
                         / (fct(j1 + j2 + j3 + 1) * fct(j1 - m1) * fct(j1 + m1) * fct(j2 - m2) * fct(j2 + m2)));
    double S = 0.0;
    for (int v = vmin; v <= vmax; ++v) {
        double sgn = ((v + j2 + m2) & 1) ? -1.0 : 1.0;
        S += sgn * fct(j2 + j3 + m1 - v) * fct(j1 - m1 + v)
             / (fct(v) * fct(j3 - j1 + j2 - v) * fct(j3 + m3 - v) * fct(v + j1 - j2 - m3));
    }
    return C * S;
}

// change-of-basis real->complex, rows = complex index (l+m), cols = real index
static void cob(int l, std::complex<double> q[5][5]) {
    for (int a = 0; a < 5; ++a) for (int b = 0; b < 5; ++b) q[a][b] = 0.0;
    const double is2 = 1.0 / std::sqrt(2.0);
    for (int m = -l; m < 0; ++m) {
        q[l + m][l - m] = is2;
        q[l + m][l + m] = std::complex<double>(0.0, -is2);
    }
    q[l][l] = 1.0;
    for (int m = 1; m <= l; ++m) {
        double sgn = (m & 1) ? -1.0 : 1.0;
        q[l + m][l + m] = sgn * is2;
        q[l + m][l - m] = std::complex<double>(0.0, sgn * is2);
    }
    std::complex<double> ph;
    switch (l & 3) {
        case 0: ph = 1.0; break;
        case 1: ph = std::complex<double>(0.0, -1.0); break;
        case 2: ph = -1.0; break;
        default: ph = std::complex<double>(0.0, 1.0); break;
    }
    for (int a = 0; a < 5; ++a) for (int b = 0; b < 5; ++b) q[a][b] *= ph;
}

// real-basis wigner 3j, normalized to unit Frobenius norm. out is d1*d2*d3 row-major [j][l][m].
static void wigner3j(int l1, int l2, int l3, double* out) {
    int d1 = 2 * l1 + 1, d2 = 2 * l2 + 1, d3 = 2 * l3 + 1;
    double csu2[5][5][5] = {};
    for (int m1 = -l1; m1 <= l1; ++m1)
        for (int m2 = -l2; m2 <= l2; ++m2)
            if (std::abs(m1 + m2) <= l3)
                csu2[l1 + m1][l2 + m2][l3 + m1 + m2] =
                    su2_cg_coeff(l1, m1, l2, m2, l3, m1 + m2) / std::sqrt(2.0 * l3 + 1.0);
    std::complex<double> Q1[5][5], Q2[5][5], Q3[5][5];
    cob(l1, Q1); cob(l2, Q2); cob(l3, Q3);
    double nrm = 0.0;
    for (int j = 0; j < d1; ++j)
        for (int l = 0; l < d2; ++l)
            for (int m = 0; m < d3; ++m) {
                std::complex<double> s = 0.0;
                for (int i = 0; i < d1; ++i)
                    for (int k = 0; k < d2; ++k)
                        for (int n = 0; n < d3; ++n)
                            s += Q1[i][j] * Q2[k][l] * std::conj(Q3[n][m]) * csu2[i][k][n];
                out[(j * d2 + l) * d3 + m] = s.real();
                nrm += s.real() * s.real();
            }
    nrm = std::sqrt(nrm);
    for (int t = 0; t < d1 * d2 * d3; ++t) out[t] /= nrm;
}

struct CGTab {
    float cA;        // 0x0->0 scalar coefficient
    float B[9];      // 1x1->0 : [i*3+j]
    float Cjk[9];    // 0x1->1 : [j*3+k]
    float Dik[9];    // 1x0->1 : [i*3+k]
    float E[27];     // 1x1->1 : [(i*3+j)*3+k]
    float F[45];     // 1x1->2 : [(i*3+j)*5+k]
};

// ---------------- device kernel ---------------------------------------------
// Layout facts (derived from reference's raw reshapes, mul1*mul2 == n == 2048):
//   out[r, c], r = u*32 + v, chunk col = chunk_base + nn*d3 + k3, nn in [0,2048)
//   x1_l0[u,nn]   = in1[(u*32 + nn/64)*256 + (nn%64)]
//   x1_l1[i,u,nn] = in1[(f/192)*256 + 64 + f%192],  f = i*131072 + u*2048 + nn
//   x2_l0[v,nn]   = in2[(v*64 + nn/32)*128 + (nn%32)]
//   x2_l1[j,v,nn] = in2[(g/96)*128 + 32 + g%96],    g = j*65536 + v*2048 + nn
// Sorted chunk bases (floats, within a row of 32768):
//   A(0e,0x0):0  B(0e,1x1):2048  C(1o,0x1):4096
//   D(1o,1x0):10240  E(1e,1x1):16384  F(2e,1x1):22528
//
// R2 change: stage each block's 16 KB output in LDS in final layout, then
// write fully-coalesced float4s. Chunk boundaries in the 1024-float4 flat
// block output (64,128,320,512,704) are all multiples of 64 -> every wave's
// chunk branch is wave-uniform and every wave stores a contiguous 1 KiB.

__global__ __launch_bounds__(256) void ftp_kernel(const float* __restrict__ in1,
                                                  const float* __restrict__ in2,
                                                  float* __restrict__ out,
                                                  CGTab cg) {
    __shared__ float lds[4096];  // 16 KB: block's output, packed chunk-major

    const int t   = threadIdx.x;
    const int nn0 = blockIdx.x * 256;
    const int nn  = nn0 + t;                        // 0..2047
    const int r   = blockIdx.y;                     // 0..2047
    const int u   = r >> 5;
    const int v   = r & 31;

    const float a0 = in1[(u * 32 + (nn >> 6)) * 256 + (nn & 63)];
    const float b0 = in2[(v * 64 + (nn >> 5)) * 128 + (nn & 31)];

    float a1[3], b1[3];
#pragma unroll
    for (int i = 0; i < 3; ++i) {
        int f = i * 131072 + u * 2048 + nn;
        int row = f / 192, col = f - row * 192;
        a1[i] = in1[row * 256 + 64 + col];
    }
#pragma unroll
    for (int j = 0; j < 3; ++j) {
        int g = j * 65536 + v * 2048 + nn;
        int row = g / 96, col = g - row * 96;
        b1[j] = in2[row * 128 + 32 + col];
    }

    // ---- compute into LDS (strides 3/5 are odd -> 2-way bank alias, free) ----
    lds[t] = cg.cA * a0 * b0;  // A

    {   // B: 0e from 1x1
        float s = 0.f;
#pragma unroll
        for (int i = 0; i < 3; ++i)
#pragma unroll
            for (int j = 0; j < 3; ++j)
                s = fmaf(cg.B[i * 3 + j], a1[i] * b1[j], s);
        lds[256 + t] = s;
    }

#pragma unroll
    for (int k = 0; k < 3; ++k) {  // C: 1o from 0x1
        float s = 0.f;
#pragma unroll
        for (int j = 0; j < 3; ++j) s = fmaf(cg.Cjk[j * 3 + k], b1[j], s);
        lds[512 + t * 3 + k] = a0 * s;
    }

#pragma unroll
    for (int k = 0; k < 3; ++k) {  // D: 1o from 1x0
        float s = 0.f;
#pragma unroll
        for (int i = 0; i < 3; ++i) s = fmaf(cg.Dik[i * 3 + k], a1[i], s);
        lds[1280 + t * 3 + k] = b0 * s;
    }

#pragma unroll
    for (int k = 0; k < 3; ++k) {  // E: 1e from 1x1
        float s = 0.f;
#pragma unroll
        for (int i = 0; i < 3; ++i)
#pragma unroll
            for (int j = 0; j < 3; ++j)
                s = fmaf(cg.E[(i * 3 + j) * 3 + k], a1[i] * b1[j], s);
        lds[2048 + t * 3 + k] = s;
    }

#pragma unroll
    for (int k = 0; k < 5; ++k) {  // F: 2e from 1x1
        float s = 0.f;
#pragma unroll
        for (int i = 0; i < 3; ++i)
#pragma unroll
            for (int j = 0; j < 3; ++j)
                s = fmaf(cg.F[(i * 3 + j) * 5 + k], a1[i] * b1[j], s);
        lds[2816 + t * 5 + k] = s;
    }

    __syncthreads();

    // ---- coalesced float4 write-out ----
    const float4* lv = (const float4*)lds;
    float4* orow4 = (float4*)(out + (size_t)r * 32768);
    const int q4 = nn0 >> 2;  // nn0/4

    // chunk table in float4 units: lds range start -> global row offset
    //   A [  0, 64)  -> 0    + q4
    //   B [ 64,128)  -> 512  + q4
    //   C [128,320)  -> 1024 + 3*q4
    //   D [320,512)  -> 2560 + 3*q4
    //   E [512,704)  -> 4096 + 3*q4
    //   F [704,1024) -> 5632 + 5*q4
#pragma unroll
    for (int s = 0; s < 4; ++s) {
        const int q = t + s * 256;   // wave-uniform chunk: boundaries on x64
        int g;
        if      (q < 64)  g = 0    + q4     + q;
        else if (q < 128) g = 512  + q4     + (q - 64);
        else if (q < 320) g = 1024 + 3 * q4 + (q - 128);
        else if (q < 512) g = 2560 + 3 * q4 + (q - 320);
        else if (q < 704) g = 4096 + 3 * q4 + (q - 512);
        else              g = 5632 + 5 * q4 + (q - 704);
        orow4[g] = lv[q];
    }
}

// ---------------- launch ------------------------------------------------------

extern "C" void kernel_launch(void* const* d_in, const int* in_sizes, int n_in,
                              void* d_out, int out_size, void* d_ws, size_t ws_size,
                              hipStream_t stream) {
    const float* in1 = (const float*)d_in[0];  // (2048, 256) fp32
    const float* in2 = (const float*)d_in[1];  // (2048, 128) fp32
    float* out = (float*)d_out;                // (2048, 32768) fp32

    // Host-side CG tables (pure CPU math — graph-capture safe; passed by value).
    CGTab cg;
    double w[45];
    const double s3 = std::sqrt(3.0), s5 = std::sqrt(5.0);

    wigner3j(0, 0, 0, w);
    cg.cA = (float)(w[0] * 1.0);

    wigner3j(1, 1, 0, w);  // [i][j][0]
    for (int i = 0; i < 3; ++i)
        for (int j = 0; j < 3; ++j) cg.B[i * 3 + j] = (float)(w[(i * 3 + j)] * 1.0);

    wigner3j(0, 1, 1, w);  // [0][j][k]
    for (int j = 0; j < 3; ++j)
        for (int k = 0; k < 3; ++k) cg.Cjk[j * 3 + k] = (float)(w[j * 3 + k] * s3);

    wigner3j(1, 0, 1, w);  // [i][0][k]
    for (int i = 0; i < 3; ++i)
        for (int k = 0; k < 3; ++k) cg.Dik[i * 3 + k] = (float)(w[i * 3 + k] * s3);

    wigner3j(1, 1, 1, w);  // [i][j][k]
    for (int t = 0; t < 27; ++t) cg.E[t] = (float)(w[t] * s3);

    wigner3j(1, 1, 2, w);  // [i][j][k], d3 = 5
    for (int t = 0; t < 45; ++t) cg.F[t] = (float)(w[t] * s5);

    dim3 grid(2048 / 256, 2048, 1);
    dim3 block(256, 1, 1);
    ftp_kernel<<<grid, block, 0, stream>>>(in1, in2, out, cg);
}